// Round 7
// baseline (210.311 us; speedup 1.0000x reference)
//
#include <hip/hip_runtime.h>
#include <hip/hip_cooperative_groups.h>

#define EPSV 1e-5f
constexpr int Bb = 4, Cc = 64, Nn = 40960, Kk = 16, Dd = 128;
constexpr int G = 4;                       // 16-pt tiles per phase-B group (even!)
constexpr int TPB = Nn / 16;               // 2560
constexpr int NTILE_A = Bb * 640;          // 2560 phase-A 64-pt tiles
constexpr int NGRP_B  = (Bb * TPB) / G;    // 2560 phase-B 64-pt groups

typedef float f32x4 __attribute__((ext_vector_type(4)));
typedef __bf16 bf16x8 __attribute__((ext_vector_type(8)));
typedef unsigned short us8 __attribute__((ext_vector_type(8)));
typedef unsigned short us4 __attribute__((ext_vector_type(4)));

__device__ inline unsigned short f2bf(float x) {
    unsigned u = __builtin_bit_cast(unsigned, x);
    u += 0x7FFFu + ((u >> 16) & 1u);   // RNE
    return (unsigned short)(u >> 16);
}

// ===========================================================================
// FUSED cooperative kernel: [phase A over tiles] grid.sync [phase B groups].
// Weight scaling/shift computed per-thread in registers (same arithmetic as
// the old prep kernel -> identical rounding). LDS phases alias one buffer.
__global__ __launch_bounds__(256, 5) void fused(
    const float* __restrict__ f, const int* __restrict__ idx,
    const float* __restrict__ w1, const float* __restrict__ g1, const float* __restrict__ b1,
    const float* __restrict__ m1, const float* __restrict__ v1,
    const float* __restrict__ w2, const float* __restrict__ g2, const float* __restrict__ b2,
    const float* __restrict__ m2, const float* __restrict__ v2,
    const float* __restrict__ w3, const float* __restrict__ g3, const float* __restrict__ b3,
    const float* __restrict__ m3, const float* __restrict__ v3,
    unsigned short* __restrict__ G1, unsigned short* __restrict__ f_t,
    float* __restrict__ out, const int nwg) {
    __shared__ __attribute__((aligned(16))) char smem[25856];
    float* s            = (float*)smem;                       // phase A: 64x65 f32
    unsigned short* sg1 = (unsigned short*)(smem + 16640);    // phase A: 64x72 bf16
    unsigned short* s_h1 = (unsigned short*)smem;             // phase B: 16x72 bf16
    float* s_out        = (float*)(smem + 2304);              // phase B: 32x133 f32

    const int tid = threadIdx.x, wave = tid >> 6, lane = tid & 63;
    const int c15 = lane & 15, q = lane >> 4;
    const int bid = blockIdx.x;

    // ---------------- phase A ----------------
    {
        const int o1 = wave * 16 + c15;
        const float sc1 = g1[o1] * rsqrtf(v1[o1] + EPSV);
        const float sh1v = b1[o1] - m1[o1] * sc1;
        bf16x8 bw1[2];
#pragma unroll
        for (int ks = 0; ks < 2; ++ks) {
            us8 t;
#pragma unroll
            for (int j = 0; j < 8; ++j) t[j] = f2bf(w1[o1 * 64 + ks * 32 + q * 8 + j] * sc1);
            bw1[ks] = __builtin_bit_cast(bf16x8, t);
        }

        for (int tt = bid; tt < NTILE_A; tt += nwg) {
            const int b = tt / 640;
            const int n0 = (tt - b * 640) * 64;

            const float* src = f + ((size_t)b * Cc + wave * 16) * Nn + n0 + lane;
#pragma unroll
            for (int i = 0; i < 16; ++i) s[(wave * 16 + i) * 65 + lane] = src[(size_t)i * Nn];
            __syncthreads();

#pragma unroll
            for (int mt = 0; mt < 4; ++mt) {
                const int pt = mt * 16 + c15;
                us8 A0, A1;
#pragma unroll
                for (int j = 0; j < 8; ++j) A0[j] = f2bf(s[(q * 8 + j) * 65 + pt]);
#pragma unroll
                for (int j = 0; j < 8; ++j) A1[j] = f2bf(s[(32 + q * 8 + j) * 65 + pt]);

                if (mt == wave) {           // transposed-f A-frags, written once
                    unsigned short* dst = f_t + ((size_t)b * Nn + n0 + pt) * 64;
                    *(uint4*)(dst + q * 8)      = __builtin_bit_cast(uint4, A0);
                    *(uint4*)(dst + 32 + q * 8) = __builtin_bit_cast(uint4, A1);
                }

                f32x4 g = {0.f, 0.f, 0.f, 0.f};
                g = __builtin_amdgcn_mfma_f32_16x16x32_bf16(__builtin_bit_cast(bf16x8, A0), bw1[0], g, 0, 0, 0);
                g = __builtin_amdgcn_mfma_f32_16x16x32_bf16(__builtin_bit_cast(bf16x8, A1), bw1[1], g, 0, 0, 0);
#pragma unroll
                for (int r = 0; r < 4; ++r)
                    sg1[(mt * 16 + q * 4 + r) * 72 + (wave * 16 + c15)] = f2bf(fmaxf(g[r] + sh1v, 0.f));
            }
            __syncthreads();

            {   // coalesced G1 store (relu'd rows)
                const int p = tid >> 2, ck = tid & 3;
                const uint4 v0 = *(const uint4*)(sg1 + p * 72 + ck * 16);
                const uint4 v1 = *(const uint4*)(sg1 + p * 72 + ck * 16 + 8);
                unsigned short* dst = G1 + ((size_t)b * Nn + n0 + p) * 64 + ck * 16;
                *(uint4*)dst = v0;
                *(uint4*)(dst + 8) = v1;
            }
            __syncthreads();                // sg1 reads done before next tile's writes
        }
    }

    // ---------------- phase-B weight frags (registers, before the sync) ----
    float sh2v[2], sh3v[2];
    bf16x8 bw2[2][2], bw3[2][2];
#pragma unroll
    for (int nt = 0; nt < 2; ++nt) {
        const int d = wave * 32 + nt * 16 + c15;
        const float sc2 = g2[d] * rsqrtf(v2[d] + EPSV);
        const float sc3 = g3[d] * rsqrtf(v3[d] + EPSV);
        sh2v[nt] = b2[d] - m2[d] * sc2;
        sh3v[nt] = b3[d] - m3[d] * sc3;
#pragma unroll
        for (int ks = 0; ks < 2; ++ks) {
            us8 t2, t3;
#pragma unroll
            for (int j = 0; j < 8; ++j) {
                t2[j] = f2bf(w2[d * 64 + ks * 32 + q * 8 + j] * sc2);
                t3[j] = f2bf(w3[d * 64 + ks * 32 + q * 8 + j] * sc3);
            }
            bw2[nt][ks] = __builtin_bit_cast(bf16x8, t2);
            bw3[nt][ks] = __builtin_bit_cast(bf16x8, t3);
        }
    }

    cooperative_groups::this_grid().sync();

    // ---------------- phase B ----------------
    const int pg = tid >> 4;                // gather-phase point 0..15
    const int cg = tid & 15;                // gather-phase channel group (4 ch)

    for (int v = bid; v < NGRP_B; v += nwg) {
        const int xcd = v & 7;              // nwg % 8 == 0 -> constant per block
        const int jb  = v >> 3;             // 0..319
        const int b   = xcd >> 1;           // 2 XCDs per batch (L2-resident G1)
        const int nb0 = (((xcd & 1) * 320) + jb) * (G * 16);

        const unsigned short* G1b = G1 + (size_t)b * Nn * 64;
        const unsigned short* ftb = f_t + (size_t)b * Nn * 64;
        const int* idxp = idx + ((size_t)b * Nn + nb0) * Kk;

        int myidx = idxp[tid];

        for (int g = 0; g < G; ++g) {
            const int n0 = nb0 + g * 16;
            const int myidxN = (g + 1 < G) ? idxp[(g + 1) * 256 + tid] : 0;

            // skip-path A-frags from f_t (contiguous)
            const unsigned short* ftrow = ftb + (size_t)(n0 + c15) * 64;
            const bf16x8 af0 = __builtin_bit_cast(bf16x8, *(const uint4*)(ftrow + q * 8));
            const bf16x8 af1 = __builtin_bit_cast(bf16x8, *(const uint4*)(ftrow + 32 + q * 8));

            // gather + sum (G1 rows pre-relu'd -> pure adds)
            float a0 = 0.f, a1 = 0.f, a2 = 0.f, a3 = 0.f;
#pragma unroll
            for (int k = 0; k < 16; ++k) {
                const int nb = __shfl(myidx, (pg & 3) * 16 + k, 64);
                const uint2 d2 = *(const uint2*)(G1b + (size_t)nb * 64 + cg * 4);
                a0 += __builtin_bit_cast(float, d2.x << 16);
                a1 += __builtin_bit_cast(float, d2.x & 0xffff0000u);
                a2 += __builtin_bit_cast(float, d2.y << 16);
                a3 += __builtin_bit_cast(float, d2.y & 0xffff0000u);
            }
            myidx = myidxN;

            __syncthreads();                 // prev s_h1/s_out reads done
            us4 hv;
            hv[0] = f2bf(a0); hv[1] = f2bf(a1); hv[2] = f2bf(a2); hv[3] = f2bf(a3);
            *(us4*)(s_h1 + pg * 72 + cg * 4) = hv;
            __syncthreads();

            const unsigned short* h1row = s_h1 + c15 * 72;
            const bf16x8 ah0 = __builtin_bit_cast(bf16x8, *(const uint4*)(h1row + q * 8));
            const bf16x8 ah1 = __builtin_bit_cast(bf16x8, *(const uint4*)(h1row + 32 + q * 8));

            const int prow = (g & 1) * 16;
#pragma unroll
            for (int nt = 0; nt < 2; ++nt) {
                f32x4 h2 = {sh2v[nt], sh2v[nt], sh2v[nt], sh2v[nt]};
                f32x4 s3 = {sh3v[nt], sh3v[nt], sh3v[nt], sh3v[nt]};
                h2 = __builtin_amdgcn_mfma_f32_16x16x32_bf16(ah0, bw2[nt][0], h2, 0, 0, 0);
                h2 = __builtin_amdgcn_mfma_f32_16x16x32_bf16(ah1, bw2[nt][1], h2, 0, 0, 0);
                s3 = __builtin_amdgcn_mfma_f32_16x16x32_bf16(af0, bw3[nt][0], s3, 0, 0, 0);
                s3 = __builtin_amdgcn_mfma_f32_16x16x32_bf16(af1, bw3[nt][1], s3, 0, 0, 0);
                const int d = wave * 32 + nt * 16 + c15;
#pragma unroll
                for (int r = 0; r < 4; ++r)
                    s_out[(prow + q * 4 + r) * 133 + d] = fmaxf(h2[r], 0.f) + fmaxf(s3[r], 0.f);
            }
            __syncthreads();

            if (g & 1) {                     // full-128B-line nt store per pair
                const int np = n0 - 16;
                const int dd = tid >> 3;
                const int ck = tid & 7;
#pragma unroll
                for (int r4 = 0; r4 < 4; ++r4) {
                    const int d = r4 * 32 + dd;
                    f32x4 vv;
#pragma unroll
                    for (int i = 0; i < 4; ++i) vv[i] = s_out[(ck * 4 + i) * 133 + d];
                    __builtin_nontemporal_store(vv, (f32x4*)(out + ((size_t)b * Dd + d) * Nn + np + ck * 4));
                }
            }
        }
    }
}

// ===========================================================================
// Fallback path (round-5 proven three-kernel pipeline), used only if
// cooperative launch is unavailable or the fused kernel can't co-reside.
__global__ __launch_bounds__(256) void prep_weights(
    const float* __restrict__ w1, const float* __restrict__ g1, const float* __restrict__ b1,
    const float* __restrict__ m1, const float* __restrict__ v1,
    const float* __restrict__ w2, const float* __restrict__ g2, const float* __restrict__ b2,
    const float* __restrict__ m2, const float* __restrict__ v2,
    const float* __restrict__ w3, const float* __restrict__ g3, const float* __restrict__ b3,
    const float* __restrict__ m3, const float* __restrict__ v3,
    unsigned short* __restrict__ w1s, unsigned short* __restrict__ w2s, unsigned short* __restrict__ w3s,
    float* __restrict__ sh1, float* __restrict__ sh2, float* __restrict__ sh3) {
    const int e = blockIdx.x * 256 + threadIdx.x;
    if (e < 4096) {
        const int o = e >> 6;
        const float sc = g1[o] * rsqrtf(v1[o] + EPSV);
        w1s[e] = f2bf(w1[e] * sc);
    } else if (e < 12288) {
        const int i = e - 4096, o = i >> 6;
        const float sc = g2[o] * rsqrtf(v2[o] + EPSV);
        w2s[i] = f2bf(w2[i] * sc);
    } else if (e < 20480) {
        const int i = e - 12288, o = i >> 6;
        const float sc = g3[o] * rsqrtf(v3[o] + EPSV);
        w3s[i] = f2bf(w3[i] * sc);
    }
    if (e < 64) sh1[e] = b1[e] - m1[e] * (g1[e] * rsqrtf(v1[e] + EPSV));
    else if (e < 192) { const int d = e - 64;  sh2[d] = b2[d] - m2[d] * (g2[d] * rsqrtf(v2[d] + EPSV)); }
    else if (e < 320) { const int d = e - 192; sh3[d] = b3[d] - m3[d] * (g3[d] * rsqrtf(v3[d] + EPSV)); }
}

__global__ __launch_bounds__(256) void passA(const float* __restrict__ f,
                                             const unsigned short* __restrict__ w1s,
                                             const float* __restrict__ sh1,
                                             unsigned short* __restrict__ G1,
                                             unsigned short* __restrict__ f_t) {
    __shared__ float s[64 * 65];
    __shared__ __attribute__((aligned(16))) unsigned short sg1[64 * 72];

    const int tid = threadIdx.x, w = tid >> 6, lane = tid & 63;
    const int c15 = lane & 15, q = lane >> 4;
    const int b = blockIdx.x / 640;
    const int n0 = (blockIdx.x % 640) * 64;

    const float* src = f + ((size_t)b * Cc + w * 16) * Nn + n0 + lane;
#pragma unroll
    for (int i = 0; i < 16; ++i) s[(w * 16 + i) * 65 + lane] = src[(size_t)i * Nn];

    const int o1 = w * 16 + c15;
    const float sh1v = sh1[o1];
    bf16x8 bw1[2];
#pragma unroll
    for (int ks = 0; ks < 2; ++ks)
        bw1[ks] = __builtin_bit_cast(bf16x8, *(const uint4*)(w1s + o1 * 64 + ks * 32 + q * 8));
    __syncthreads();

#pragma unroll
    for (int mt = 0; mt < 4; ++mt) {
        const int pt = mt * 16 + c15;
        us8 A0, A1;
#pragma unroll
        for (int j = 0; j < 8; ++j) A0[j] = f2bf(s[(q * 8 + j) * 65 + pt]);
#pragma unroll
        for (int j = 0; j < 8; ++j) A1[j] = f2bf(s[(32 + q * 8 + j) * 65 + pt]);
        if (mt == w) {
            unsigned short* dst = f_t + ((size_t)b * Nn + n0 + pt) * 64;
            *(uint4*)(dst + q * 8)      = __builtin_bit_cast(uint4, A0);
            *(uint4*)(dst + 32 + q * 8) = __builtin_bit_cast(uint4, A1);
        }
        f32x4 g = {0.f, 0.f, 0.f, 0.f};
        g = __builtin_amdgcn_mfma_f32_16x16x32_bf16(__builtin_bit_cast(bf16x8, A0), bw1[0], g, 0, 0, 0);
        g = __builtin_amdgcn_mfma_f32_16x16x32_bf16(__builtin_bit_cast(bf16x8, A1), bw1[1], g, 0, 0, 0);
#pragma unroll
        for (int r = 0; r < 4; ++r)
            sg1[(mt * 16 + q * 4 + r) * 72 + o1] = f2bf(fmaxf(g[r] + sh1v, 0.f));
    }
    __syncthreads();

    {
        const int p = tid >> 2, ck = tid & 3;
        const uint4 v0 = *(const uint4*)(sg1 + p * 72 + ck * 16);
        const uint4 v1 = *(const uint4*)(sg1 + p * 72 + ck * 16 + 8);
        unsigned short* dst = G1 + ((size_t)b * Nn + n0 + p) * 64 + ck * 16;
        *(uint4*)dst = v0;
        *(uint4*)(dst + 8) = v1;
    }
}

__global__ __launch_bounds__(256, 4) void passB(
    const unsigned short* __restrict__ G1, const unsigned short* __restrict__ f_t,
    const int* __restrict__ idx,
    const unsigned short* __restrict__ w2s, const unsigned short* __restrict__ w3s,
    const float* __restrict__ sh2, const float* __restrict__ sh3,
    float* __restrict__ out) {
    __shared__ __attribute__((aligned(16))) unsigned short s_h1[16 * 72];
    __shared__ float s_out[32 * 133];

    const int tid  = threadIdx.x;
    const int wave = tid >> 6;
    const int lane = tid & 63;
    const int c15  = lane & 15;
    const int q    = lane >> 4;
    const int pg   = tid >> 4;
    const int cg   = tid & 15;

    const int xcd = blockIdx.x & 7;
    const int jb  = blockIdx.x >> 3;
    const int b   = xcd >> 1;
    const int nb0 = (((xcd & 1) * 320) + jb) * (G * 16);

    float sh2v[2], sh3v[2];
    bf16x8 bw2[2][2], bw3[2][2];
#pragma unroll
    for (int nt = 0; nt < 2; ++nt) {
        const int d = wave * 32 + nt * 16 + c15;
        sh2v[nt] = sh2[d];
        sh3v[nt] = sh3[d];
#pragma unroll
        for (int ks = 0; ks < 2; ++ks) {
            bw2[nt][ks] = __builtin_bit_cast(bf16x8, *(const uint4*)(w2s + d * 64 + ks * 32 + q * 8));
            bw3[nt][ks] = __builtin_bit_cast(bf16x8, *(const uint4*)(w3s + d * 64 + ks * 32 + q * 8));
        }
    }

    const unsigned short* G1b = G1 + (size_t)b * Nn * 64;
    const unsigned short* ftb = f_t + (size_t)b * Nn * 64;
    const int* idxp = idx + ((size_t)b * Nn + nb0) * Kk;

    int myidx = idxp[tid];

    for (int g = 0; g < G; ++g) {
        const int n0 = nb0 + g * 16;
        const int myidxN = (g + 1 < G) ? idxp[(g + 1) * 256 + tid] : 0;

        const unsigned short* ftrow = ftb + (size_t)(n0 + c15) * 64;
        const bf16x8 af0 = __builtin_bit_cast(bf16x8, *(const uint4*)(ftrow + q * 8));
        const bf16x8 af1 = __builtin_bit_cast(bf16x8, *(const uint4*)(ftrow + 32 + q * 8));

        float a0 = 0.f, a1 = 0.f, a2 = 0.f, a3 = 0.f;
#pragma unroll
        for (int k = 0; k < 16; ++k) {
            const int nb = __shfl(myidx, (pg & 3) * 16 + k, 64);
            const uint2 d2 = *(const uint2*)(G1b + (size_t)nb * 64 + cg * 4);
            a0 += __builtin_bit_cast(float, d2.x << 16);
            a1 += __builtin_bit_cast(float, d2.x & 0xffff0000u);
            a2 += __builtin_bit_cast(float, d2.y << 16);
            a3 += __builtin_bit_cast(float, d2.y & 0xffff0000u);
        }
        myidx = myidxN;

        __syncthreads();
        us4 hv;
        hv[0] = f2bf(a0); hv[1] = f2bf(a1); hv[2] = f2bf(a2); hv[3] = f2bf(a3);
        *(us4*)(s_h1 + pg * 72 + cg * 4) = hv;
        __syncthreads();

        const unsigned short* h1row = s_h1 + c15 * 72;
        const bf16x8 ah0 = __builtin_bit_cast(bf16x8, *(const uint4*)(h1row + q * 8));
        const bf16x8 ah1 = __builtin_bit_cast(bf16x8, *(const uint4*)(h1row + 32 + q * 8));

        const int prow = (g & 1) * 16;
#pragma unroll
        for (int nt = 0; nt < 2; ++nt) {
            f32x4 h2 = {sh2v[nt], sh2v[nt], sh2v[nt], sh2v[nt]};
            f32x4 s3 = {sh3v[nt], sh3v[nt], sh3v[nt], sh3v[nt]};
            h2 = __builtin_amdgcn_mfma_f32_16x16x32_bf16(ah0, bw2[nt][0], h2, 0, 0, 0);
            h2 = __builtin_amdgcn_mfma_f32_16x16x32_bf16(ah1, bw2[nt][1], h2, 0, 0, 0);
            s3 = __builtin_amdgcn_mfma_f32_16x16x32_bf16(af0, bw3[nt][0], s3, 0, 0, 0);
            s3 = __builtin_amdgcn_mfma_f32_16x16x32_bf16(af1, bw3[nt][1], s3, 0, 0, 0);
            const int d = wave * 32 + nt * 16 + c15;
#pragma unroll
            for (int r = 0; r < 4; ++r)
                s_out[(prow + q * 4 + r) * 133 + d] = fmaxf(h2[r], 0.f) + fmaxf(s3[r], 0.f);
        }
        __syncthreads();

        if (g & 1) {
            const int np = n0 - 16;
            const int dd = tid >> 3;
            const int ck = tid & 7;
#pragma unroll
            for (int r4 = 0; r4 < 4; ++r4) {
                const int d = r4 * 32 + dd;
                f32x4 v;
#pragma unroll
                for (int i = 0; i < 4; ++i) v[i] = s_out[(ck * 4 + i) * 133 + d];
                __builtin_nontemporal_store(v, (f32x4*)(out + ((size_t)b * Dd + d) * Nn + np + ck * 4));
            }
        }
    }
}

extern "C" void kernel_launch(void* const* d_in, const int* in_sizes, int n_in,
                              void* d_out, int out_size, void* d_ws, size_t ws_size,
                              hipStream_t stream) {
    const float* feature = (const float*)d_in[0];
    const int*   neigh   = (const int*)d_in[1];
    const float* w1 = (const float*)d_in[2];
    const float* g1 = (const float*)d_in[3];
    const float* b1 = (const float*)d_in[4];
    const float* m1 = (const float*)d_in[5];
    const float* v1 = (const float*)d_in[6];
    const float* w2 = (const float*)d_in[7];
    const float* g2 = (const float*)d_in[8];
    const float* b2 = (const float*)d_in[9];
    const float* m2 = (const float*)d_in[10];
    const float* v2 = (const float*)d_in[11];
    const float* w3 = (const float*)d_in[12];
    const float* g3 = (const float*)d_in[13];
    const float* b3 = (const float*)d_in[14];
    const float* m3 = (const float*)d_in[15];
    const float* v3 = (const float*)d_in[16];
    float* out = (float*)d_out;

    const size_t SZ_G1 = (size_t)Bb * Nn * 64 * 2;        // 20,971,520 B
    const size_t SZ_FT = (size_t)Bb * Nn * 64 * 2;        // 20,971,520 B

    char* ws = (char*)d_ws;
    unsigned short* G1  = (unsigned short*)ws;
    unsigned short* f_t = (unsigned short*)(ws + SZ_G1);
    char* wbase = ws + SZ_G1 + SZ_FT;

    // one-time capability probe (host-side queries only; capture-safe)
    static int coop_grid = []() -> int {
        int dev = 0;
        if (hipGetDevice(&dev) != hipSuccess) return 0;
        int attr = 0;
        if (hipDeviceGetAttribute(&attr, hipDeviceAttributeCooperativeLaunch, dev) != hipSuccess || !attr)
            return 0;
        int nb = 0;
        if (hipOccupancyMaxActiveBlocksPerMultiprocessor(&nb, fused, 256, 0) != hipSuccess)
            return 0;
        int ncu = 0;
        if (hipDeviceGetAttribute(&ncu, hipDeviceAttributeMultiprocessorCount, dev) != hipSuccess)
            return 0;
        const long cap = (long)nb * (long)ncu;
        if (cap >= 1280) return 1280;      // perfect balance: 2 A-tiles, 2 B-groups
        if (cap >= 1024) return 1024;      // safe 4 blocks/CU
        return 0;
    }();

    if (coop_grid > 0) {
        int nwg = coop_grid;
        void* args[] = {
            (void*)&feature, (void*)&neigh,
            (void*)&w1, (void*)&g1, (void*)&b1, (void*)&m1, (void*)&v1,
            (void*)&w2, (void*)&g2, (void*)&b2, (void*)&m2, (void*)&v2,
            (void*)&w3, (void*)&g3, (void*)&b3, (void*)&m3, (void*)&v3,
            (void*)&G1, (void*)&f_t, (void*)&out, (void*)&nwg};
        (void)hipLaunchCooperativeKernel((const void*)fused, dim3(nwg), dim3(256), args, 0, stream);
    } else {
        unsigned short* w1s = (unsigned short*)wbase;
        unsigned short* w2s = (unsigned short*)(wbase + 8192);
        unsigned short* w3s = (unsigned short*)(wbase + 24576);
        float* sh1 = (float*)(wbase + 40960);
        float* sh2 = (float*)(wbase + 41216);
        float* sh3 = (float*)(wbase + 41728);
        prep_weights<<<80, 256, 0, stream>>>(w1, g1, b1, m1, v1, w2, g2, b2, m2, v2,
                                             w3, g3, b3, m3, v3, w1s, w2s, w3s, sh1, sh2, sh3);
        passA<<<Bb * 640, 256, 0, stream>>>(feature, w1s, sh1, G1, f_t);
        passB<<<(Bb * TPB) / G, 256, 0, stream>>>(G1, f_t, neigh, w2s, w3s,
                                                  sh2, sh3, out);
    }
}